// Round 6
// baseline (107.401 us; speedup 1.0000x reference)
//
#include <hip/hip_runtime.h>

#define BATCH 4
#define NROWS 2048
#define IN_DIM 1024
#define OUT_DIM 512
#define NBLK 256
#define RPB 32              // rows per block
#define W2SL 16             // w2 producer blocks / d-slices

#define LD_RLX(p)    __hip_atomic_load((p),  __ATOMIC_RELAXED, __HIP_MEMORY_SCOPE_AGENT)
#define ST_RLX(p,v)  __hip_atomic_store((p), (v), __ATOMIC_RELAXED, __HIP_MEMORY_SCOPE_AGENT)
#define LD_ACQ(p)    __hip_atomic_load((p),  __ATOMIC_ACQUIRE, __HIP_MEMORY_SCOPE_AGENT)
#define ST_REL(p,v)  __hip_atomic_store((p), (v), __ATOMIC_RELEASE, __HIP_MEMORY_SCOPE_AGENT)
#define ADD_REL(p,v) __hip_atomic_fetch_add((p), (v), __ATOMIC_ACQ_REL, __HIP_MEMORY_SCOPE_AGENT)

// ws layout: u32 flags[16] | w2part[16*1024] | Zc[256] | yu[256*1024] | y[4096] | c[2048]
__global__ void __launch_bounds__(512, 2)
mega(const float* __restrict__ x,
     const float* __restrict__ fc_w,
     const float* __restrict__ fc_b,
     const float* __restrict__ attn_w,
     unsigned int* __restrict__ flags,
     float* __restrict__ out)
{
    float* fbase  = (float*)(flags + 16);
    float* w2part = fbase;                       // 16384
    float* Zc     = w2part + W2SL * IN_DIM;      // 256
    float* yu     = Zc + NBLK;                   // 262144
    float* y      = yu + (size_t)NBLK * IN_DIM;  // 4096
    float* cbuf   = y + BATCH * IN_DIM;          // 2048
    unsigned int* w2_cnt = flags + 0;
    unsigned int* yu_cnt = flags + 1;            // [4]
    unsigned int* y_flag = flags + 5;            // [4]
    unsigned int* c_cnt  = flags + 9;            // [4]

    const int bid = blockIdx.x, t = threadIdx.x;
    const int w = t >> 6, lane = t & 63;
    const int b = bid >> 6, ch = bid & 63;

    __shared__ float w2s[IN_DIM];                // 4 KB
    __shared__ float4 sbuf[8 * 256];             // 32 KB
    __shared__ float zbuf[8];
    __shared__ float zinv_s;
    __shared__ int merger_s;

    // ---------- phase 1: blocks 0..15 produce w2part slices ----------
    if (bid < W2SL) {
        int d0 = bid << 5;                       // 32 d's per slice
#pragma unroll
        for (int h = 0; h < 2; ++h) {
            int col = (h << 9) + t;
            float acc = 0.f;
#pragma unroll 8
            for (int j = 0; j < 32; ++j)
                acc += fc_w[(size_t)(d0 + j) * IN_DIM + col] * attn_w[OUT_DIM + d0 + j];
            ST_RLX(&w2part[(bid << 10) + col], acc);
        }
        __syncthreads();
        if (t == 0) ADD_REL(w2_cnt, 1u);
    }
    // all blocks wait for w2, then merge slices into LDS
    if (t == 0) { while (LD_ACQ(w2_cnt) < W2SL) __builtin_amdgcn_s_sleep(2); }
    __syncthreads();
#pragma unroll
    for (int h = 0; h < 2; ++h) {
        int col = (h << 9) + t;
        float s = 0.f;
#pragma unroll
        for (int p = 0; p < W2SL; ++p)
            s += LD_RLX(&w2part[(p << 10) + col]);
        w2s[col] = s;
    }
    __syncthreads();

    // ---------- phase 2: chunk pass (x read once, in registers) ----------
    const float4* x4 = (const float4*)x;
    const float4* w2s4 = (const float4*)w2s;
    const float4 u0 = w2s4[lane],       u1 = w2s4[lane + 64],
                 u2 = w2s4[lane + 128], u3 = w2s4[lane + 192];

    size_t row0 = (size_t)bid * RPB + (w << 2);
    float4 a0 = {0,0,0,0}, a1 = {0,0,0,0}, a2 = {0,0,0,0}, a3 = {0,0,0,0};
    float zw = 0.f;
#pragma unroll
    for (int r = 0; r < 4; ++r) {
        size_t base = (row0 + r) << 8;
        float4 v0 = x4[base + lane];
        float4 v1 = x4[base + lane + 64];
        float4 v2 = x4[base + lane + 128];
        float4 v3 = x4[base + lane + 192];
        float d = v0.x*u0.x + v0.y*u0.y + v0.z*u0.z + v0.w*u0.w
                + v1.x*u1.x + v1.y*u1.y + v1.z*u1.z + v1.w*u1.w
                + v2.x*u2.x + v2.y*u2.y + v2.z*u2.z + v2.w*u2.w
                + v3.x*u3.x + v3.y*u3.y + v3.z*u3.z + v3.w*u3.w;
#pragma unroll
        for (int off = 32; off; off >>= 1) d += __shfl_xor(d, off, 64);
        float e = __expf(d);                  // |d| ~ few units: safe fp32, exact softmax algebra
        zw += e;
        a0.x += e*v0.x; a0.y += e*v0.y; a0.z += e*v0.z; a0.w += e*v0.w;
        a1.x += e*v1.x; a1.y += e*v1.y; a1.z += e*v1.z; a1.w += e*v1.w;
        a2.x += e*v2.x; a2.y += e*v2.y; a2.z += e*v2.z; a2.w += e*v2.w;
        a3.x += e*v3.x; a3.y += e*v3.y; a3.z += e*v3.z; a3.w += e*v3.w;
    }
    sbuf[(w << 8) + lane]       = a0;
    sbuf[(w << 8) + lane + 64]  = a1;
    sbuf[(w << 8) + lane + 128] = a2;
    sbuf[(w << 8) + lane + 192] = a3;
    if (lane == 0) zbuf[w] = zw;
    __syncthreads();

    // publish yu (coalesced: thread t -> floats t, t+512) and Zc
    const float* sbf = (const float*)sbuf;
#pragma unroll
    for (int h = 0; h < 2; ++h) {
        int i = (h << 9) + t;
        float s = 0.f;
#pragma unroll
        for (int wv = 0; wv < 8; ++wv) s += sbf[(wv << 10) + i];
        ST_RLX(&yu[((size_t)bid << 10) + i], s);
    }
    if (t == 0) {
        float z = 0.f;
#pragma unroll
        for (int i = 0; i < 8; ++i) z += zbuf[i];
        ST_RLX(&Zc[bid], z);
    }
    __syncthreads();

    // ---------- phase 3: last block per batch merges y ----------
    if (t == 0) {
        unsigned int ret = ADD_REL(&yu_cnt[b], 1u);
        merger_s = (ret == 63u);
    }
    __syncthreads();
    if (merger_s) {
        float col0 = 0.f, col1 = 0.f;
        const float* yub = yu + ((size_t)b << 16);   // 64 chunks * 1024
#pragma unroll 8
        for (int c0 = 0; c0 < 64; ++c0) {
            col0 += LD_RLX(&yub[(c0 << 10) + t]);
            col1 += LD_RLX(&yub[(c0 << 10) + t + 512]);
        }
        if (w == 0) {
            float z = LD_RLX(&Zc[(b << 6) + lane]);
#pragma unroll
            for (int off = 32; off; off >>= 1) z += __shfl_xor(z, off, 64);
            if (lane == 0) zinv_s = 1.f / z;
        }
        __syncthreads();
        float invZ = zinv_s;
        ST_RLX(&y[(b << 10) + t],       col0 * invZ);
        ST_RLX(&y[(b << 10) + t + 512], col1 * invZ);
        __syncthreads();
        if (t == 0) ST_REL(&y_flag[b], 1u);
    }

    // all blocks wait for their batch's y, load to LDS (reuse w2s)
    if (t == 0) { while (LD_ACQ(&y_flag[b]) == 0u) __builtin_amdgcn_s_sleep(2); }
    __syncthreads();
    w2s[t]       = LD_RLX(&y[(b << 10) + t]);
    w2s[t + 512] = LD_RLX(&y[(b << 10) + t + 512]);
    __syncthreads();

    // ---------- phase 4: c (wave w of block computes d = ch*8 + w) ----------
    {
        int d = (ch << 3) + w;
        const float4* fr = (const float4*)fc_w + ((size_t)d << 8);
        const float4* ys4 = (const float4*)w2s;
        float4 f0 = fr[lane], f1 = fr[lane + 64], f2 = fr[lane + 128], f3 = fr[lane + 192];
        float4 y0 = ys4[lane], y1 = ys4[lane + 64], y2 = ys4[lane + 128], y3 = ys4[lane + 192];
        float s = f0.x*y0.x + f0.y*y0.y + f0.z*y0.z + f0.w*y0.w
                + f1.x*y1.x + f1.y*y1.y + f1.z*y1.z + f1.w*y1.w
                + f2.x*y2.x + f2.y*y2.y + f2.z*y2.z + f2.w*y2.w
                + f3.x*y3.x + f3.y*y3.y + f3.z*y3.z + f3.w*y3.w;
#pragma unroll
        for (int off = 32; off; off >>= 1) s += __shfl_xor(s, off, 64);
        if (lane == 0) ST_RLX(&cbuf[(b << 9) + d], s + fc_b[d]);
    }
    __syncthreads();
    if (t == 0) ADD_REL(&c_cnt[b], 1u);

    // wait for the batch's full c, then broadcast own 32 rows
    if (t == 0) { while (LD_ACQ(&c_cnt[b]) < 64u) __builtin_amdgcn_s_sleep(2); }
    __syncthreads();
    w2s[t] = LD_RLX(&cbuf[(b << 9) + t]);        // t<512 covers all 512 c's
    __syncthreads();

    {
        const float4* cs4 = (const float4*)w2s;
        float4* o4 = (float4*)out + ((size_t)bid << 12);   // 32 rows * 128 f4
#pragma unroll
        for (int j = 0; j < 8; ++j) {
            int idx = (j << 9) + t;
            o4[idx] = cs4[idx & 127];
        }
    }
}

extern "C" void kernel_launch(void* const* d_in, const int* in_sizes, int n_in,
                              void* d_out, int out_size, void* d_ws, size_t ws_size,
                              hipStream_t stream) {
    const float* x      = (const float*)d_in[0];
    const float* fc_w   = (const float*)d_in[1];
    const float* fc_b   = (const float*)d_in[2];
    const float* attn_w = (const float*)d_in[3];
    // attn_b (d_in[4]) cancels in the softmax — unused.
    unsigned int* flags = (unsigned int*)d_ws;
    float* out = (float*)d_out;

    // zero the sync counters every call (deterministic, graph-capture legal)
    hipMemsetAsync(flags, 0, 64, stream);
    mega<<<NBLK, 512, 0, stream>>>(x, fc_w, fc_b, attn_w, flags, out);
}

// Round 7
// 30.630 us; speedup vs baseline: 3.5065x; 3.5065x over previous
//
#include <hip/hip_runtime.h>

#define BATCH 4
#define NROWS 2048
#define IN_DIM 1024
#define OUT_DIM 512
#define DSPLIT 16
#define NCHUNK 256          // chunks total (64 per batch)
#define RPB 32              // rows per chunk

// ---- K1: w2part[ds][col] = sum_{d in slice} fc_w[d][col] * a2[d] ------
// 64 blocks (16 d-slices x 4 col-groups), 32 loads/thread.
__global__ void __launch_bounds__(256)
k1_w2part(const float* __restrict__ fc_w,
          const float* __restrict__ attn_w,
          float* __restrict__ w2part) {
    int ds = blockIdx.x >> 2, cg = blockIdx.x & 3;
    int col = (cg << 8) + threadIdx.x;
    int d0 = ds << 5;
    float acc = 0.f;
#pragma unroll 8
    for (int j = 0; j < 32; ++j)
        acc += fc_w[(size_t)(d0 + j) * IN_DIM + col] * attn_w[OUT_DIM + d0 + j];
    w2part[(ds << 10) + col] = acc;
}

// ---- K2: per-chunk flash pass: yu_c = sum_r e^{s2_r} x_r, Zc = sum e --
// 256 blocks x 512 threads; 8 waves x 4 rows; x read ONCE, held in regs.
__global__ void __launch_bounds__(512)
k2_chunk(const float* __restrict__ x,
         const float* __restrict__ w2part,
         float* __restrict__ yu,
         float* __restrict__ Zc) {
    const int bid = blockIdx.x, t = threadIdx.x;
    const int w = t >> 6, lane = t & 63;
    __shared__ float w2s[IN_DIM];                 // 4 KB
    __shared__ float4 sbuf[8 * 256];              // 32 KB
    __shared__ float zbuf[8];

    if (t < 256) {
        const float4* wp = (const float4*)w2part;
        float4 s = {0.f, 0.f, 0.f, 0.f};
#pragma unroll
        for (int ds = 0; ds < DSPLIT; ++ds) {
            float4 v = wp[(ds << 8) + t];
            s.x += v.x; s.y += v.y; s.z += v.z; s.w += v.w;
        }
        ((float4*)w2s)[t] = s;
    }
    __syncthreads();

    const float4* x4 = (const float4*)x;
    const float4* w2s4 = (const float4*)w2s;
    const float4 u0 = w2s4[lane],       u1 = w2s4[lane + 64],
                 u2 = w2s4[lane + 128], u3 = w2s4[lane + 192];

    size_t row0 = (size_t)bid * RPB + (w << 2);
    float4 a0 = {0,0,0,0}, a1 = {0,0,0,0}, a2 = {0,0,0,0}, a3 = {0,0,0,0};
    float zw = 0.f;
#pragma unroll
    for (int r = 0; r < 4; ++r) {
        size_t base = (row0 + r) << 8;
        float4 v0 = x4[base + lane];
        float4 v1 = x4[base + lane + 64];
        float4 v2 = x4[base + lane + 128];
        float4 v3 = x4[base + lane + 192];
        float d = v0.x*u0.x + v0.y*u0.y + v0.z*u0.z + v0.w*u0.w
                + v1.x*u1.x + v1.y*u1.y + v1.z*u1.z + v1.w*u1.w
                + v2.x*u2.x + v2.y*u2.y + v2.z*u2.z + v2.w*u2.w
                + v3.x*u3.x + v3.y*u3.y + v3.z*u3.z + v3.w*u3.w;
#pragma unroll
        for (int off = 32; off; off >>= 1) d += __shfl_xor(d, off, 64);
        float e = __expf(d);            // |s2| <~ 5: safe fp32; max-term cancels exactly
        zw += e;
        a0.x += e*v0.x; a0.y += e*v0.y; a0.z += e*v0.z; a0.w += e*v0.w;
        a1.x += e*v1.x; a1.y += e*v1.y; a1.z += e*v1.z; a1.w += e*v1.w;
        a2.x += e*v2.x; a2.y += e*v2.y; a2.z += e*v2.z; a2.w += e*v2.w;
        a3.x += e*v3.x; a3.y += e*v3.y; a3.z += e*v3.z; a3.w += e*v3.w;
    }
    sbuf[(w << 8) + lane]       = a0;
    sbuf[(w << 8) + lane + 64]  = a1;
    sbuf[(w << 8) + lane + 128] = a2;
    sbuf[(w << 8) + lane + 192] = a3;
    if (lane == 0) zbuf[w] = zw;
    __syncthreads();

    if (t < 256) {
        float4 s = {0.f, 0.f, 0.f, 0.f};
#pragma unroll
        for (int i = 0; i < 8; ++i) {
            float4 v = sbuf[(i << 8) + t];
            s.x += v.x; s.y += v.y; s.z += v.z; s.w += v.w;
        }
        ((float4*)(yu + ((size_t)bid << 10)))[t] = s;
        if (t == 0) {
            float z = 0.f;
#pragma unroll
            for (int i = 0; i < 8; ++i) z += zbuf[i];
            Zc[bid] = z;
        }
    }
}

// ---- K3: y merge (redundant per block, parallel) + c slice -------------
// 128 blocks: (b, ds in [0,32)); each computes 16 c-values.
__global__ void __launch_bounds__(256)
k3_yc(const float* __restrict__ yu,
      const float* __restrict__ Zc,
      const float* __restrict__ fc_w,
      const float* __restrict__ fc_b,
      float* __restrict__ cb) {
    const int b = blockIdx.x >> 5, ds = blockIdx.x & 31;
    const int t = threadIdx.x, w = t >> 6, lane = t & 63;
    __shared__ float ys[IN_DIM];
    __shared__ float zsh;

    if (w == 0) {
        float z = Zc[(b << 6) + lane];
#pragma unroll
        for (int off = 32; off; off >>= 1) z += __shfl_xor(z, off, 64);
        if (lane == 0) zsh = 1.f / z;
    }

    // merge this batch's 64 chunk partials: thread t owns float4 col t
    const float4* yu4 = (const float4*)yu + ((size_t)b << 14);
    float4 acc = {0.f, 0.f, 0.f, 0.f};
#pragma unroll 8
    for (int c = 0; c < 64; ++c) {
        float4 v = yu4[(c << 8) + t];
        acc.x += v.x; acc.y += v.y; acc.z += v.z; acc.w += v.w;
    }
    __syncthreads();
    const float invZ = zsh;
    acc.x *= invZ; acc.y *= invZ; acc.z *= invZ; acc.w *= invZ;
    ((float4*)ys)[t] = acc;
    __syncthreads();

    const float4* ys4 = (const float4*)ys;
    const float4 y0 = ys4[lane],       y1 = ys4[lane + 64],
                 y2 = ys4[lane + 128], y3 = ys4[lane + 192];
#pragma unroll
    for (int q = 0; q < 4; ++q) {
        int d = (ds << 4) + (w << 2) + q;
        const float4* fr = (const float4*)fc_w + ((size_t)d << 8);
        float4 f0 = fr[lane], f1 = fr[lane + 64], f2 = fr[lane + 128], f3 = fr[lane + 192];
        float s = f0.x*y0.x + f0.y*y0.y + f0.z*y0.z + f0.w*y0.w
                + f1.x*y1.x + f1.y*y1.y + f1.z*y1.z + f1.w*y1.w
                + f2.x*y2.x + f2.y*y2.y + f2.z*y2.z + f2.w*y2.w
                + f3.x*y3.x + f3.y*y3.y + f3.z*y3.z + f3.w*y3.w;
#pragma unroll
        for (int off = 32; off; off >>= 1) s += __shfl_xor(s, off, 64);
        if (lane == 0) cb[(b << 9) + d] = s + fc_b[d];
    }
}

// ---- K4: out[b,n,:] = c[b,:] broadcast (8 rows per block) --------------
__global__ void __launch_bounds__(256)
k4_bcast(const float* __restrict__ cb, float4* __restrict__ out) {
    const int bid = blockIdx.x, t = threadIdx.x;
    const int b = bid >> 8;
    __shared__ float4 cs[128];
    if (t < 128) cs[t] = ((const float4*)cb)[(b << 7) + t];
    __syncthreads();
    float4* o = out + ((size_t)bid << 10);
#pragma unroll
    for (int j = 0; j < 4; ++j) {
        int idx = (j << 8) + t;
        o[idx] = cs[idx & 127];
    }
}

extern "C" void kernel_launch(void* const* d_in, const int* in_sizes, int n_in,
                              void* d_out, int out_size, void* d_ws, size_t ws_size,
                              hipStream_t stream) {
    const float* x      = (const float*)d_in[0];
    const float* fc_w   = (const float*)d_in[1];
    const float* fc_b   = (const float*)d_in[2];
    const float* attn_w = (const float*)d_in[3];
    // attn_b (d_in[4]) cancels in the softmax — unused.

    float* wsf    = (float*)d_ws;
    float* w2part = wsf;                               // 16384
    float* Zc     = w2part + DSPLIT * IN_DIM;          // 256
    float* yu     = Zc + NCHUNK;                       // 262144
    float* cb     = yu + (size_t)NCHUNK * IN_DIM;      // 2048
    float* out    = (float*)d_out;                     // total ws: 1.12 MB

    k1_w2part<<<64,     256, 0, stream>>>(fc_w, attn_w, w2part);
    k2_chunk <<<NCHUNK, 512, 0, stream>>>(x, w2part, yu, Zc);
    k3_yc    <<<128,    256, 0, stream>>>(yu, Zc, fc_w, fc_b, cb);
    k4_bcast <<<1024,   256, 0, stream>>>(cb, (float4*)out);
}